// Round 9
// baseline (222.178 us; speedup 1.0000x reference)
//
#include <hip/hip_runtime.h>
#include <math.h>

#define NPTS   4096   // points per set (n == m)
#define NPROJ  2000   // projections
#define NB     1024   // threads per block (16 waves)
#define NMERGE 8192   // n + m
#define VPT    8      // values per thread (in registers)

// XOR swizzle: low-5 bits xor'd with chunk index (chunk = i>>5). Bijective.
// Strided store (thread t, elems 8t+e): each bank gets exactly 2 lanes (free).
// 3 VALU (shr+and+xor) vs 5 for the old rotate swizzle.
__device__ __forceinline__ int sw(int i) {
    return i ^ ((i >> 5) & 31);
}

// Bitonic local merge of 8 in-register elements, steps j=4..1, uniform direction.
__device__ __forceinline__ void local_merge(float v[VPT], bool asc) {
    #pragma unroll
    for (int j = 4; j >= 1; j >>= 1) {
        #pragma unroll
        for (int e = 0; e < VPT; ++e) {
            if ((e & j) == 0) {
                float a = v[e], b = v[e | j];
                float mn = fminf(a, b), mx = fmaxf(a, b);
                v[e]     = asc ? mn : mx;
                v[e | j] = asc ? mx : mn;
            }
        }
    }
}

// R9: NB=1024/VPT=8. R2..R8 all plateaued at ~13 waves/CU regardless of
// VGPR(48)/LDS(32K) headroom -> evidence of a per-CU workgroup-count cap,
// not a resource cap. 16-wave blocks turn ~2 resident WGs into 32 waves/CU
// (HW max). Per-thread state halves (~40 VGPR live -> fits the 64-VGPR /
// 8-waves-per-SIMD budget without hints). Sort tree: wave runs of 512, then
// 3 merge-path rounds (512->1024->2048->4096); k=512 forced ascending
// (512-block is bitonic there). Values bit-identical to R8.
__global__ __launch_bounds__(NB) void swd_kernel(
    const float* __restrict__ Xs, const float* __restrict__ Xt,
    const float* __restrict__ Us, float* __restrict__ out)
{
    // keys: sorted u || sorted v (swizzled addressing). Exactly 32 KiB.
    // After the final merge it is dead and its head is reused:
    //   ired = (int*)keys [0..31]  : 16 wave mins, 16 wave maxs of level c
    //   red  = keys + 32  [32..47] : bisection sum per iteration (ds_add)
    //   wred = keys + 48  [48..63] : final 16 wave partials
    __shared__ float keys[NMERGE];

    const int tid  = threadIdx.x;
    const int arr  = tid >> 9;       // 0 = Xs half, 1 = Xt half
    const int c    = tid & 511;      // chunk index within this array (8 elems/chunk)
    const int lane = tid & 63;
    const int wid  = tid >> 6;       // 0..15
    const int p    = blockIdx.x;

    const float u00 = Us[p*6+0], u01 = Us[p*6+1];
    const float u10 = Us[p*6+2], u11 = Us[p*6+3];
    const float u20 = Us[p*6+4], u21 = Us[p*6+5];

    const float pi_f   = 3.14159265358979323846f;
    const float inv2pi = 0.15915494309189535f;

    const float* __restrict__ X = arr ? Xt : Xs;

    // ---- angles into registers (atan2 is scale-invariant; F.normalize skipped) ----
    float v[VPT];
    {
        const float4* X4 = (const float4*)(X + c * (VPT * 3));  // 24 floats, 16B aligned
        #pragma unroll
        for (int t = 0; t < 2; ++t) {
            float4 q0 = X4[t*3+0], q1 = X4[t*3+1], q2 = X4[t*3+2];
            #define ANG(x,y,z) ((atan2f(-((x)*u01+(y)*u11+(z)*u21), \
                                        -((x)*u00+(y)*u10+(z)*u20)) + pi_f) * inv2pi)
            v[t*4+0] = ANG(q0.x, q0.y, q0.z);
            v[t*4+1] = ANG(q0.w, q1.x, q1.y);
            v[t*4+2] = ANG(q1.z, q1.w, q2.x);
            v[t*4+3] = ANG(q2.y, q2.z, q2.w);
            #undef ANG
        }
    }

    // ---- phases k=2..4: intra-thread, compile-time directions ----
    #pragma unroll
    for (int k = 2; k <= 4; k <<= 1) {
        #pragma unroll
        for (int j = k >> 1; j >= 1; j >>= 1) {
            #pragma unroll
            for (int e = 0; e < VPT; ++e) {
                if ((e & j) == 0) {
                    bool asc = ((e & k) == 0);
                    float a = v[e], b = v[e | j];
                    float mn = fminf(a, b), mx = fmaxf(a, b);
                    v[e]     = asc ? mn : mx;
                    v[e | j] = asc ? mx : mn;
                }
            }
        }
    }

    // ---- phase k=8: fully local, direction uniform per thread ----
    local_merge(v, (c & 1) == 0);

    // ---- phases k=16..512: within-wave shfl_xor exchanges + local merge ----
    // g = c*8 + e; asc = ((g & k)==0) = ((c & (k>>3))==0). k=512 forced
    // ascending (each aligned 512-block is asc-256||desc-256 = bitonic), so
    // all 16 wave-runs emerge ascending & merge-ready.
    #pragma unroll
    for (int k = 16; k <= 512; k <<= 1) {
        bool asc = (k == 512) || ((c & (k >> 3)) == 0);
        #pragma unroll
        for (int d = k >> 4; d >= 1; d >>= 1) {     // j = k/2 .. 8
            bool keepmin = (((c & d) == 0) == asc);
            #pragma unroll
            for (int e = 0; e < VPT; ++e) {
                float o = __shfl_xor(v[e], d, 64);
                v[e] = keepmin ? fminf(v[e], o) : fmaxf(v[e], o);
            }
        }
        local_merge(v, asc);
    }

    // ---- store the 16 ascending 512-runs ----
    #pragma unroll
    for (int e = 0; e < VPT; ++e) keys[sw(tid * VPT + e)] = v[e];
    __syncthreads();

    // ---- merge-path rounds: 512->1024->2048->4096 within each half ----
    // Output identity: Ab + dd = tid*8, so writes land back in place.
    #define MERGE_ROUND(L, AB, DD)                                          \
    {                                                                       \
        const int Ab = (AB);                                                \
        const int Bb = Ab + (L);                                            \
        const int dd = (DD);                                                \
        int lo = dd > (L) ? dd - (L) : 0;                                   \
        int hi = dd < (L) ? dd : (L);                                       \
        while (lo < hi) {                                                   \
            int mid = (lo + hi) >> 1;                                       \
            if (keys[sw(Ab + mid)] <= keys[sw(Bb + (dd - 1 - mid))])        \
                lo = mid + 1; else hi = mid;                                \
        }                                                                   \
        int i = lo, j = dd - lo;                                            \
        const float INFV = __builtin_inff();                                \
        float cu = (i < (L)) ? keys[sw(Ab + i)] : INFV;                     \
        float cv = (j < (L)) ? keys[sw(Bb + j)] : INFV;                     \
        _Pragma("unroll")                                                   \
        for (int s = 0; s < VPT; ++s) {                                     \
            bool take = (cu <= cv);                                         \
            v[s] = fminf(cu, cv);                                           \
            if (take) { ++i; cu = (i < (L)) ? keys[sw(Ab + i)] : INFV; }    \
            else      { ++j; cv = (j < (L)) ? keys[sw(Bb + j)] : INFV; }    \
        }                                                                   \
        __syncthreads();                                                    \
        _Pragma("unroll")                                                   \
        for (int e = 0; e < VPT; ++e) keys[sw(tid * VPT + e)] = v[e];       \
        __syncthreads();                                                    \
    }

    MERGE_ROUND(512,  arr * 4096 + (c >> 7) * 1024, (c & 127) * VPT)
    MERGE_ROUND(1024, arr * 4096 + (c >> 8) * 2048, (c & 255) * VPT)
    MERGE_ROUND(2048, arr * 4096,                   c * VPT)
    #undef MERGE_ROUND
    // keys now holds: sorted u at [0,4096), sorted v at [4096,8192).

    // ---- merge-path merge of u||v; (delta, level-offset) into registers ----
    int c_init;
    int offmin = 16, offmax = -16;                   // per-thread range of c offsets
    float offf[VPT];
    {
        const int d0 = tid * VPT;
        int lo = d0 > NPTS ? d0 - NPTS : 0;
        int hi = d0 < NPTS ? d0 : NPTS;
        while (lo < hi) {                     // ties: u first (stable argsort)
            int mid = (lo + hi) >> 1;
            if (keys[sw(mid)] <= keys[sw(NPTS + (d0 - 1 - mid))]) lo = mid + 1; else hi = mid;
        }
        int i = lo, j = d0 - lo;
        c_init = i - j;
        const float FMAXV = 3.402823466e+38f;
        float cu = (i < NPTS) ? keys[sw(i)] : FMAXV;
        float cv = (j < NPTS) ? keys[sw(NPTS + j)] : FMAXV;
        #pragma unroll
        for (int s = 0; s < VPT; ++s) {
            float cur;
            if (cu <= cv) { cur = cu; ++i; cu = (i < NPTS) ? keys[sw(i)] : FMAXV; }
            else          { cur = cv; ++j; cv = (j < NPTS) ? keys[sw(NPTS + j)] : FMAXV; }
            float nxt = fminf(cu, cv);
            if (nxt == FMAXV) nxt = 1.0f;     // vals_pad appends 1.0
            v[s] = nxt - cur;                 // delta (>= 0)
            int off = (i - j) - c_init;       // in [-8, 8]
            offmin = min(offmin, off);
            offmax = max(offmax, off);
            offf[s] = (float)off;
        }
    }

    __syncthreads();   // keys reads done everywhere; safe to reuse keys as scratch
    int*   ired = (int*)keys;       // [0..31]: 16 wave mins, 16 wave maxs
    float* red  = keys + 32;        // [32..47]: per-iteration bisection sums
    float* wred = keys + 48;        // [48..63]: final wave partials

    // ---- block min/max of level c ----
    int cmn = c_init + offmin, cmx = c_init + offmax;
    #pragma unroll
    for (int o = 32; o >= 1; o >>= 1) {
        cmn = min(cmn, __shfl_xor(cmn, o, 64));
        cmx = max(cmx, __shfl_xor(cmx, o, 64));
    }
    if (lane == 0) { ired[wid] = cmn; ired[16 + wid] = cmx; }
    if (tid < 16) red[tid] = 0.0f;            // zero bisection accumulators
    __syncthreads();
    cmn = ired[0]; cmx = ired[16];
    #pragma unroll
    for (int w = 1; w < 16; ++w) {
        cmn = min(cmn, ired[w]);
        cmx = max(cmx, ired[16 + w]);
    }

    // ---- level median c* via integer bisection over attained range ----
    // c* = smallest c with W(<= c) >= 0.5. Invariant: W(lo) < 0.5 <= W(hi).
    int lo_c = cmn - 1, hi_c = cmx;
    int it = 0;
    #pragma unroll 1
    while (hi_c - lo_c > 1) {
        const int mid = (lo_c + hi_c) >> 1;   // uniform across block
        const float thrf = (float)(mid - c_init);
        float s_loc = 0.0f;
        #pragma unroll
        for (int s = 0; s < VPT; ++s)
            s_loc += (offf[s] <= thrf) ? v[s] : 0.0f;
        #pragma unroll
        for (int o = 32; o >= 1; o >>= 1) s_loc += __shfl_down(s_loc, o, 64);
        if (lane == 0) atomicAdd(&red[it], s_loc);   // ds_add_f32, 16 lane0s
        __syncthreads();
        float S = red[it];                           // broadcast read
        if (S >= 0.5f) hi_c = mid; else lo_c = mid;
        ++it;
    }
    const int cstar = hi_c;

    // ---- w1 = (1/4096) * sum delta * |c - c*| ----
    float part = 0.0f;
    {
        const float thrf = (float)(cstar - c_init);
        #pragma unroll
        for (int s = 0; s < VPT; ++s)
            part += v[s] * fabsf(offf[s] - thrf);   // |x| is a free input modifier
    }
    #pragma unroll
    for (int o = 32; o >= 1; o >>= 1) part += __shfl_down(part, o, 64);
    if (lane == 0) wred[wid] = part;
    __syncthreads();
    if (tid == 0) {
        float w1 = 0.0f;
        #pragma unroll
        for (int w = 0; w < 16; ++w) w1 += wred[w];
        w1 *= (1.0f / 4096.0f);
        atomicAdd(out, w1 * (1.0f / (float)NPROJ));
    }
}

extern "C" void kernel_launch(void* const* d_in, const int* in_sizes, int n_in,
                              void* d_out, int out_size, void* d_ws, size_t ws_size,
                              hipStream_t stream) {
    const float* Xs = (const float*)d_in[0];
    const float* Xt = (const float*)d_in[1];
    const float* Us = (const float*)d_in[2];
    float* out = (float*)d_out;

    hipMemsetAsync(out, 0, sizeof(float), stream);
    swd_kernel<<<NPROJ, NB, 0, stream>>>(Xs, Xt, Us, out);
}